// Round 10
// baseline (259.404 us; speedup 1.0000x reference)
//
#include <hip/hip_runtime.h>

typedef float f32x4 __attribute__((ext_vector_type(4)));
typedef float f32x2 __attribute__((ext_vector_type(2)));

#define T_LEN   262144
#define NTAG    128
#define LCH     8                  // chunk length
#define BURN    8                  // burn-in steps
#define NSTEP   16                 // LCH + BURN
#define NCHUNK  (T_LEN / LCH)      // 32768
#define NWAVE   (NCHUNK / 16)      // 2048
#define NFWDB   (NWAVE / 4)        // 512 forward blocks
#define NSCOREB 256
#define C9      6.23832462503951f  // 9 ln2
#define K63LN2  43.66827237527655f // 63 ln2 (7 counted steps x 9ln2, chunk 0)
#define K72LN2  49.90659700060892f // 72 ln2 (8 counted steps x 9ln2)

// ===========================================================================
// PROBES (diagnostic; results go to ws[8..11], never touch d_out)
// ===========================================================================

// ---- p_stream: clean linear grid-stride streaming of emit -----------------
__global__ __launch_bounds__(256, 2) void p_stream(
    const float4* __restrict__ em4, double* __restrict__ ws)
{
  float4 s4 = {0.f, 0.f, 0.f, 0.f};
#pragma unroll 8
  for (int i = blockIdx.x * 256 + threadIdx.x; i < T_LEN * 32; i += 512 * 256) {
    const float4 v = em4[i];
    s4.x += v.x; s4.y += v.y; s4.z += v.z; s4.w += v.w;
  }
  float r = s4.x + s4.y + s4.z + s4.w;
#pragma unroll
  for (int off = 1; off < 64; off <<= 1) r += __shfl_xor(r, off, 64);
  if ((threadIdx.x & 63) == 0) atomicAdd(&ws[9], (double)r);
}

// ---- p_gather: R6's exact load pattern, compute stripped ------------------
__global__ __launch_bounds__(256, 2) void p_gather(
    const float* __restrict__ emit, double* __restrict__ ws)
{
  const int w = threadIdx.x >> 6, l = threadIdx.x & 63;
  const int col = l & 15, g = l >> 4;
  const int gw = blockIdx.x * 4 + w;
  const int gc = gw * 16 + col;
  const int t0 = (gc == 0) ? 1 : (gc * LCH - BURN);
  float4 pf[2][8];
  {
    const float* e0 = emit + ((size_t)t0 << 7) + 4 * g;
    const float* e1 = emit + ((size_t)(t0 + 1) << 7) + 4 * g;
#pragma unroll
    for (int rt = 0; rt < 8; ++rt) {
      pf[0][rt] = *(const float4*)(e0 + 16 * rt);
      pf[1][rt] = *(const float4*)(e1 + 16 * rt);
    }
  }
  float4 acc = {0.f, 0.f, 0.f, 0.f};
#pragma unroll
  for (int s = 0; s < NSTEP; ++s) {
#pragma unroll
    for (int rt = 0; rt < 8; ++rt) {
      acc.x += pf[s & 1][rt].x; acc.y += pf[s & 1][rt].y;
      acc.z += pf[s & 1][rt].z; acc.w += pf[s & 1][rt].w;
    }
    if (s < NSTEP - 2) {
      const float* ep = emit + ((size_t)(t0 + s + 2) << 7) + 4 * g;
#pragma unroll
      for (int rt = 0; rt < 8; ++rt) pf[s & 1][rt] = *(const float4*)(ep + 16 * rt);
    }
  }
  float r = acc.x + acc.y + acc.z + acc.w;
#pragma unroll
  for (int off = 1; off < 64; off <<= 1) r += __shfl_xor(r, off, 64);
  if (l == 0) atomicAdd(&ws[10], (double)r);
}

// ---- p_gather2: same pattern, 4-deep prefetch (MLP sensitivity) -----------
__global__ __launch_bounds__(256, 2) void p_gather2(
    const float* __restrict__ emit, double* __restrict__ ws)
{
  const int w = threadIdx.x >> 6, l = threadIdx.x & 63;
  const int col = l & 15, g = l >> 4;
  const int gw = blockIdx.x * 4 + w;
  const int gc = gw * 16 + col;
  const int t0 = (gc == 0) ? 1 : (gc * LCH - BURN);
  float4 pf[4][8];
#pragma unroll
  for (int d = 0; d < 4; ++d) {
    const float* ep = emit + ((size_t)(t0 + d) << 7) + 4 * g;
#pragma unroll
    for (int rt = 0; rt < 8; ++rt) pf[d][rt] = *(const float4*)(ep + 16 * rt);
  }
  float4 acc = {0.f, 0.f, 0.f, 0.f};
#pragma unroll
  for (int s = 0; s < NSTEP; ++s) {
#pragma unroll
    for (int rt = 0; rt < 8; ++rt) {
      acc.x += pf[s & 3][rt].x; acc.y += pf[s & 3][rt].y;
      acc.z += pf[s & 3][rt].z; acc.w += pf[s & 3][rt].w;
    }
    if (s < NSTEP - 4) {
      const float* ep = emit + ((size_t)(t0 + s + 4) << 7) + 4 * g;
#pragma unroll
      for (int rt = 0; rt < 8; ++rt) pf[s & 3][rt] = *(const float4*)(ep + 16 * rt);
    }
  }
  float r = acc.x + acc.y + acc.z + acc.w;
#pragma unroll
  for (int off = 1; off < 64; off <<= 1) r += __shfl_xor(r, off, 64);
  if (l == 0) atomicAdd(&ws[11], (double)r);
}

// ---- p_rec: pure recurrence chain (no global loads in loop) ---------------
__global__ __launch_bounds__(256, 2) void p_rec(
    const uint4* __restrict__ q4, double* __restrict__ ws)
{
  const int l = threadIdx.x & 63;
  long a[8][4];
#pragma unroll
  for (int rt = 0; rt < 8; ++rt)
#pragma unroll
    for (int kp = 0; kp < 2; ++kp) {
      uint4 v = q4[(rt * 2 + kp) * 64 + l];
      a[rt][2 * kp]     = (long)(((unsigned long long)v.y << 32) | v.x);
      a[rt][2 * kp + 1] = (long)(((unsigned long long)v.w << 32) | v.z);
    }
  unsigned dwE = (unsigned)(threadIdx.x * 2654435761u + blockIdx.x * 40503u);
  asm volatile("" : "+v"(dwE));            // opaque to the compiler
  long bb[4];
#pragma unroll
  for (int kt = 0; kt < 4; ++kt) {
    unsigned lo = (unsigned)__builtin_amdgcn_cvt_pk_fp8_f32(1.f, 1.f, 0, false);
    lo = (unsigned)__builtin_amdgcn_cvt_pk_fp8_f32(1.f, 1.f, (int)lo, true);
    bb[kt] = (long)(((unsigned long long)lo << 32) | lo);
  }
  float accv = 0.f;
#pragma unroll
  for (int s = 0; s < NSTEP; ++s) {
    f32x4 c[8];
#pragma unroll
    for (int rt = 0; rt < 8; ++rt) c[rt] = (f32x4){0.f, 0.f, 0.f, 0.f};
#pragma unroll
    for (int kt = 0; kt < 4; ++kt)
#pragma unroll
      for (int rt = 0; rt < 8; ++rt)
        c[rt] = __builtin_amdgcn_mfma_f32_16x16x32_fp8_fp8(a[rt][kt], bb[kt], c[rt], 0, 0, 0);
    float wv[8][4];
#pragma unroll
    for (int rt = 0; rt < 8; ++rt) {
      const unsigned dw = dwE ^ (unsigned)(s * 0x9E3779B9u + rt * 101u);
      const f32x2 lo = __builtin_amdgcn_cvt_pk_f32_fp8((int)dw, false);
      const f32x2 hi = __builtin_amdgcn_cvt_pk_f32_fp8((int)dw, true);
      wv[rt][0] = c[rt][0] * lo[0];
      wv[rt][1] = c[rt][1] * lo[1];
      wv[rt][2] = c[rt][2] * hi[0];
      wv[rt][3] = c[rt][3] * hi[1];
    }
    if ((s & 3) == 3) {
      float vm = wv[0][0];
#pragma unroll
      for (int rt = 0; rt < 8; ++rt)
#pragma unroll
        for (int r = 0; r < 4; ++r) vm = fmaxf(vm, wv[rt][r]);
      vm = fmaxf(vm, __shfl_xor(vm, 16, 64));
      vm = fmaxf(vm, __shfl_xor(vm, 32, 64));
      accv += __logf(vm);
      const float rinv = __builtin_amdgcn_rcpf(vm);
#pragma unroll
      for (int rt = 0; rt < 8; ++rt)
#pragma unroll
        for (int r = 0; r < 4; ++r) wv[rt][r] *= rinv;
    }
#pragma unroll
    for (int kt = 0; kt < 4; ++kt) {
      unsigned lo = (unsigned)__builtin_amdgcn_cvt_pk_fp8_f32(wv[2*kt][0], wv[2*kt][1], 0, false);
      lo = (unsigned)__builtin_amdgcn_cvt_pk_fp8_f32(wv[2*kt][2], wv[2*kt][3], (int)lo, true);
      unsigned hi = (unsigned)__builtin_amdgcn_cvt_pk_fp8_f32(wv[2*kt+1][0], wv[2*kt+1][1], 0, false);
      hi = (unsigned)__builtin_amdgcn_cvt_pk_fp8_f32(wv[2*kt+1][2], wv[2*kt+1][3], (int)hi, true);
      bb[kt] = (long)(((unsigned long long)hi << 32) | lo);
    }
  }
  float r = accv + (float)(bb[0] & 0xff) + (float)(bb[1] & 0xff)
                 + (float)(bb[2] & 0xff) + (float)(bb[3] & 0xff);
#pragma unroll
  for (int off = 1; off < 64; off <<= 1) r += __shfl_xor(r, off, 64);
  if (l == 0) atomicAdd(&ws[8], (double)r);
}

// ===========================================================================
// REAL PATH — R6 structure with per-step C9 scaling + per-chunk constants
// ===========================================================================
__global__ void crf_setup(const float* __restrict__ trans, uint4* __restrict__ q4)
{
  const int l = threadIdx.x;           // 64 threads
  const int col = l & 15, grp = l >> 4;
  for (int rt = 0; rt < 8; ++rt) {
    const int outtag = 16 * rt + col;
    for (int kp = 0; kp < 2; ++kp) {
      unsigned r[4];
      for (int h = 0; h < 2; ++h) {
        const int kt = kp * 2 + h;
        float q[8];
        for (int j = 0; j < 8; ++j) {
          const int k = 32 * kt + 4 * grp + (j & 3) + 16 * (j >> 2);
          q[j] = __expf(trans[k * NTAG + outtag]);
        }
        unsigned lo = (unsigned)__builtin_amdgcn_cvt_pk_fp8_f32(q[0], q[1], 0, false);
        lo = (unsigned)__builtin_amdgcn_cvt_pk_fp8_f32(q[2], q[3], (int)lo, true);
        unsigned hi = (unsigned)__builtin_amdgcn_cvt_pk_fp8_f32(q[4], q[5], 0, false);
        hi = (unsigned)__builtin_amdgcn_cvt_pk_fp8_f32(q[6], q[7], (int)hi, true);
        r[h * 2] = lo; r[h * 2 + 1] = hi;
      }
      q4[(rt * 2 + kp) * 64 + l] = make_uint4(r[0], r[1], r[2], r[3]);
    }
  }
}

__global__ __launch_bounds__(256, 2) void crf_fwd(
    const float* __restrict__ emit, const float* __restrict__ strans,
    const float* __restrict__ etrans, const uint4* __restrict__ q4,
    double* __restrict__ ws)
{
  const int w_id = threadIdx.x >> 6;
  const int l    = threadIdx.x & 63;
  const int col  = l & 15;
  const int grp  = l >> 4;
  const int gw   = blockIdx.x * 4 + w_id;
  const int gc   = gw * 16 + col;

  long a[8][4];
#pragma unroll
  for (int rt = 0; rt < 8; ++rt)
#pragma unroll
    for (int kp = 0; kp < 2; ++kp) {
      uint4 v = q4[(rt * 2 + kp) * 64 + l];
      a[rt][2 * kp]     = (long)(((unsigned long long)v.y << 32) | v.x);
      a[rt][2 * kp + 1] = (long)(((unsigned long long)v.w << 32) | v.z);
    }

  float m0 = 0.f;
  long b[4];
  {
    float u[8][4];
    if (gw == 0) {
      float vm = -1e30f;
#pragma unroll
      for (int rt = 0; rt < 8; ++rt)
#pragma unroll
        for (int r = 0; r < 4; ++r) {
          const int tag = 16 * rt + 4 * grp + r;
          u[rt][r] = (col == 0) ? (strans[tag] + emit[tag]) : 0.f;
          vm = fmaxf(vm, u[rt][r]);
        }
      vm = fmaxf(vm, __shfl_xor(vm, 16, 64));
      vm = fmaxf(vm, __shfl_xor(vm, 32, 64));
      m0 = vm;                                 // per-col max; col0 = dc_0
#pragma unroll
      for (int rt = 0; rt < 8; ++rt)
#pragma unroll
        for (int r = 0; r < 4; ++r)
          u[rt][r] = (col == 0) ? __expf(u[rt][r] - vm) : 1.0f;
    } else {
#pragma unroll
      for (int rt = 0; rt < 8; ++rt)
#pragma unroll
        for (int r = 0; r < 4; ++r) u[rt][r] = 1.0f;
    }
#pragma unroll
    for (int kt = 0; kt < 4; ++kt) {
      unsigned lo = (unsigned)__builtin_amdgcn_cvt_pk_fp8_f32(u[2*kt][0], u[2*kt][1], 0, false);
      lo = (unsigned)__builtin_amdgcn_cvt_pk_fp8_f32(u[2*kt][2], u[2*kt][3], (int)lo, true);
      unsigned hi = (unsigned)__builtin_amdgcn_cvt_pk_fp8_f32(u[2*kt+1][0], u[2*kt+1][1], 0, false);
      hi = (unsigned)__builtin_amdgcn_cvt_pk_fp8_f32(u[2*kt+1][2], u[2*kt+1][3], (int)hi, true);
      b[kt] = (long)(((unsigned long long)hi << 32) | lo);
    }
  }

  const int t0 = (gc == 0) ? 1 : (gc * LCH - BURN);
  float4 pf[2][8];
  {
    const float* e0 = emit + ((size_t)t0 << 7) + 4 * grp;
    const float* e1 = emit + ((size_t)(t0 + 1) << 7) + 4 * grp;
#pragma unroll
    for (int rt = 0; rt < 8; ++rt) {
      pf[0][rt] = *(const float4*)(e0 + 16 * rt);
      pf[1][rt] = *(const float4*)(e1 + 16 * rt);
    }
  }

  float acc = 0.f;

#pragma unroll
  for (int s = 0; s < NSTEP; ++s) {
    float e[8][4];
#pragma unroll
    for (int rt = 0; rt < 8; ++rt) {
      e[rt][0] = __expf(pf[s & 1][rt].x - C9);
      e[rt][1] = __expf(pf[s & 1][rt].y - C9);
      e[rt][2] = __expf(pf[s & 1][rt].z - C9);
      e[rt][3] = __expf(pf[s & 1][rt].w - C9);
    }
    if (s < NSTEP - 2) {
      const float* ep = emit + ((size_t)(t0 + s + 2) << 7) + 4 * grp;
#pragma unroll
      for (int rt = 0; rt < 8; ++rt) pf[s & 1][rt] = *(const float4*)(ep + 16 * rt);
    }

    f32x4 c[8];
#pragma unroll
    for (int rt = 0; rt < 8; ++rt) c[rt] = (f32x4){0.f, 0.f, 0.f, 0.f};
#pragma unroll
    for (int kt = 0; kt < 4; ++kt)
#pragma unroll
      for (int rt = 0; rt < 8; ++rt)
        c[rt] = __builtin_amdgcn_mfma_f32_16x16x32_fp8_fp8(a[rt][kt], b[kt], c[rt], 0, 0, 0);

    float wv[8][4];
    float vm = -1e30f;
#pragma unroll
    for (int rt = 0; rt < 8; ++rt)
#pragma unroll
      for (int r = 0; r < 4; ++r) {
        wv[rt][r] = c[rt][r] * e[rt][r];
        vm = fmaxf(vm, wv[rt][r]);
      }
    vm = fmaxf(vm, __shfl_xor(vm, 16, 64));
    vm = fmaxf(vm, __shfl_xor(vm, 32, 64));
    const bool on = (gc == 0) ? (s <= LCH - 2) : (s >= BURN);
    if (on) acc += __logf(vm);
    const float rinv = __frcp_rn(vm);
#pragma unroll
    for (int kt = 0; kt < 4; ++kt) {
      const float s0 = wv[2*kt][0] * rinv,   s1 = wv[2*kt][1] * rinv;
      const float s2 = wv[2*kt][2] * rinv,   s3 = wv[2*kt][3] * rinv;
      const float s4 = wv[2*kt+1][0] * rinv, s5 = wv[2*kt+1][1] * rinv;
      const float s6 = wv[2*kt+1][2] * rinv, s7 = wv[2*kt+1][3] * rinv;
      unsigned lo = (unsigned)__builtin_amdgcn_cvt_pk_fp8_f32(s0, s1, 0, false);
      lo = (unsigned)__builtin_amdgcn_cvt_pk_fp8_f32(s2, s3, (int)lo, true);
      unsigned hi = (unsigned)__builtin_amdgcn_cvt_pk_fp8_f32(s4, s5, 0, false);
      hi = (unsigned)__builtin_amdgcn_cvt_pk_fp8_f32(s6, s7, (int)hi, true);
      b[kt] = (long)(((unsigned long long)hi << 32) | lo);
    }

    if (s == NSTEP - 1 && gw == NWAVE - 1) {
      float lse = 0.f;
#pragma unroll
      for (int rt = 0; rt < 8; ++rt)
#pragma unroll
        for (int r = 0; r < 4; ++r)
          lse += (wv[rt][r] * rinv) * __expf(etrans[16 * rt + 4 * grp + r]);
      lse += __shfl_xor(lse, 16, 64);
      lse += __shfl_xor(lse, 32, 64);
      if (l == 15) atomicAdd(&ws[2], (double)lse);
    }
  }

  // FIX: per-chunk compensation for the 2^-9/step scaling on counted steps.
  // chunk 0: 7 counted logs (s=0..6) + dc_0=m0 -> +m0 + 63ln2
  // others : 8 counted logs (s=8..15)         -> +72ln2
  const float accf = acc + ((gc == 0) ? (m0 + K63LN2) : K72LN2);
  float av = (grp == 0) ? accf : 0.f;
#pragma unroll
  for (int off = 1; off < 64; off <<= 1) av += __shfl_xor(av, off, 64);
  if (l == 0) atomicAdd(&ws[0], (double)av);
}

__global__ void crf_score(const float* __restrict__ emit, const int* __restrict__ y,
                          const float* __restrict__ trans, const float* __restrict__ strans,
                          const float* __restrict__ etrans, double* __restrict__ ws)
{
  __shared__ float sred[4];
  int idx0 = blockIdx.x * 256 + threadIdx.x;
  float v = 0.f;
  for (int t = idx0; t < T_LEN - 1; t += NSCOREB * 256) {
    int yt = y[t], yn = y[t + 1];
    v += trans[yt * NTAG + yn] + emit[(size_t)t * NTAG + yt];
  }
  if (idx0 == 0) {
    int yl = y[T_LEN - 1];
    v += strans[y[0]] + etrans[yl] + emit[(size_t)(T_LEN - 1) * NTAG + yl];
  }
#pragma unroll
  for (int off = 1; off < 64; off <<= 1) v += __shfl_xor(v, off, 64);
  if ((threadIdx.x & 63) == 0) sred[threadIdx.x >> 6] = v;
  __syncthreads();
  if (threadIdx.x == 0)
    atomicAdd(&ws[1], (double)(sred[0] + sred[1] + sred[2] + sred[3]));
}

__global__ void crf_final(const double* __restrict__ ws, float* __restrict__ out)
{
  out[0] = (float)(ws[0] + log(ws[2]) - ws[1]);
}

// ---------------------------------------------------------------------------
extern "C" void kernel_launch(void* const* d_in, const int* in_sizes, int n_in,
                              void* d_out, int out_size, void* d_ws, size_t ws_size,
                              hipStream_t stream)
{
  const float* emit   = (const float*)d_in[0];
  const int*   y      = (const int*)d_in[1];
  const float* trans  = (const float*)d_in[2];
  const float* strans = (const float*)d_in[3];
  const float* etrans = (const float*)d_in[4];
  float*  out = (float*)d_out;
  double* ws  = (double*)d_ws;
  uint4*  q4  = (uint4*)((char*)d_ws + 128);   // 16 KB fp8 A-fragments

  hipMemsetAsync(ws, 0, 12 * sizeof(double), stream);
  crf_setup<<<dim3(1), dim3(64), 0, stream>>>(trans, q4);

  // ---- probes (diagnostic; write only to ws[8..11]) ----
  p_rec    <<<dim3(NFWDB), dim3(256), 0, stream>>>(q4, ws);
  p_stream <<<dim3(NFWDB), dim3(256), 0, stream>>>((const float4*)emit, ws);
  p_gather <<<dim3(NFWDB), dim3(256), 0, stream>>>(emit, ws);
  p_gather2<<<dim3(NFWDB), dim3(256), 0, stream>>>(emit, ws);

  // ---- real path ----
  crf_score<<<dim3(NSCOREB), dim3(256), 0, stream>>>(emit, y, trans, strans, etrans, ws);
  crf_fwd  <<<dim3(NFWDB), dim3(256), 0, stream>>>(emit, strans, etrans, q4, ws);
  crf_final<<<dim3(1), dim3(1), 0, stream>>>(ws, out);
}

// Round 11
// 125.521 us; speedup vs baseline: 2.0666x; 2.0666x over previous
//
#include <hip/hip_runtime.h>

typedef float f32x4 __attribute__((ext_vector_type(4)));
typedef float f32x2 __attribute__((ext_vector_type(2)));

#define T_LEN   262144
#define NTAG    128
#define LCH     8
#define BURN    8
#define NSTEP   16
#define NCHUNK  (T_LEN / LCH)      // 32768
#define NWAVE   (NCHUNK / 16)      // 2048
#define NFWDB   (NWAVE / 4)        // 512
#define NPREPB  1024
#define NSCOREB 256
// fallback-path constants (R10)
#define C9      6.23832462503951f
#define K63LN2  43.66827237527655f
#define K72LN2  49.90659700060892f

// ===========================================================================
// FAST PATH
// E layout: row = 128 fp8 bytes; tag (16rt+4g+r) lives at byte
// h*64 + g*16 + rtl*4 + r  (h=rt>>2, rtl=rt&3).  A lane (col,g) then reads
// 2x16B at row*128 + g*16 (+64); a wave instruction covers 16 rows x 64 B
// aligned contiguous segments (4x fewer segments and bytes than R6).
// ===========================================================================

// ---- prep: E = fp8(exp(emit-1)) + path score + A-fragment setup -----------
__global__ __launch_bounds__(256) void crf_prep(
    const float* __restrict__ emit, const int* __restrict__ y,
    const float* __restrict__ trans, const float* __restrict__ strans,
    const float* __restrict__ etrans, unsigned* __restrict__ Ed,
    uint4* __restrict__ q4, double* __restrict__ ws)
{
  const int gid    = blockIdx.x * 256 + threadIdx.x;
  const int stride = NPREPB * 256;                 // 262144
  const float4* __restrict__ em4 = (const float4*)emit;

  // phase 1: streaming convert (p_stream pattern: linear, unrolled)
#pragma unroll 8
  for (int idx = gid; idx < T_LEN * 32; idx += stride) {
    const float4 v = em4[idx];
    const float e0 = __expf(v.x - 1.0f), e1 = __expf(v.y - 1.0f);
    const float e2 = __expf(v.z - 1.0f), e3 = __expf(v.w - 1.0f);
    unsigned d = (unsigned)__builtin_amdgcn_cvt_pk_fp8_f32(e0, e1, 0, false);
    d = (unsigned)__builtin_amdgcn_cvt_pk_fp8_f32(e2, e3, (int)d, true);
    const int q = idx & 31, row = idx >> 5;
    const int dd = ((q >> 4) << 4) | ((q & 3) << 2) | ((q >> 2) & 3);
    Ed[(row << 5) + dd] = d;
  }

  // phase 2: supervised path score
  {
    float v = 0.f;
    for (int t = gid; t < T_LEN - 1; t += stride) {
      const int yt = y[t], yn = y[t + 1];
      v += trans[yt * NTAG + yn] + emit[(size_t)t * NTAG + yt];
    }
    if (gid == 0) {
      const int yl = y[T_LEN - 1];
      v += strans[y[0]] + etrans[yl] + emit[(size_t)(T_LEN - 1) * NTAG + yl];
    }
#pragma unroll
    for (int off = 1; off < 64; off <<= 1) v += __shfl_xor(v, off, 64);
    if ((threadIdx.x & 63) == 0) atomicAdd(&ws[1], (double)v);
  }

  // phase 3: A = fp8(exp(trans)) fragments (block 0, wave 0)
  if (blockIdx.x == 0 && threadIdx.x < 64) {
    const int l = threadIdx.x, col = l & 15, grp = l >> 4;
    for (int rt = 0; rt < 8; ++rt) {
      const int outtag = 16 * rt + col;
      for (int kp = 0; kp < 2; ++kp) {
        unsigned r[4];
        for (int h = 0; h < 2; ++h) {
          const int kt = kp * 2 + h;
          float qv[8];
          for (int j = 0; j < 8; ++j) {
            const int k = 32 * kt + 4 * grp + (j & 3) + 16 * (j >> 2);
            qv[j] = __expf(trans[k * NTAG + outtag]);
          }
          unsigned lo = (unsigned)__builtin_amdgcn_cvt_pk_fp8_f32(qv[0], qv[1], 0, false);
          lo = (unsigned)__builtin_amdgcn_cvt_pk_fp8_f32(qv[2], qv[3], (int)lo, true);
          unsigned hi = (unsigned)__builtin_amdgcn_cvt_pk_fp8_f32(qv[4], qv[5], 0, false);
          hi = (unsigned)__builtin_amdgcn_cvt_pk_fp8_f32(qv[6], qv[7], (int)hi, true);
          r[h * 2] = lo; r[h * 2 + 1] = hi;
        }
        q4[(rt * 2 + kp) * 64 + l] = make_uint4(r[0], r[1], r[2], r[3]);
      }
    }
  }
}

// ---- main: wave-autonomous recurrence on fp8 E ----------------------------
__global__ __launch_bounds__(256, 2) void crf_main(
    const float* __restrict__ emit, const float* __restrict__ strans,
    const float* __restrict__ etrans, const unsigned char* __restrict__ Eb,
    const uint4* __restrict__ q4, double* __restrict__ ws,
    float* __restrict__ out)
{
  const int w_id = threadIdx.x >> 6;
  const int l    = threadIdx.x & 63;
  const int col  = l & 15;
  const int g    = l >> 4;
  const int gw   = blockIdx.x * 4 + w_id;
  const int gc   = gw * 16 + col;

  // A fragments
  long a[8][4];
#pragma unroll
  for (int rt = 0; rt < 8; ++rt)
#pragma unroll
    for (int kp = 0; kp < 2; ++kp) {
      uint4 v = q4[(rt * 2 + kp) * 64 + l];
      a[rt][2 * kp]     = (long)(((unsigned long long)v.y << 32) | v.x);
      a[rt][2 * kp + 1] = (long)(((unsigned long long)v.w << 32) | v.z);
    }

  // init state: chunk 0 exact; others p = 1
  float m0 = 0.f;
  long b[4];
  {
    float u[8][4];
    if (gw == 0) {
      float vm = -1e30f;
#pragma unroll
      for (int rt = 0; rt < 8; ++rt)
#pragma unroll
        for (int r = 0; r < 4; ++r) {
          const int tag = 16 * rt + 4 * g + r;
          u[rt][r] = (col == 0) ? (strans[tag] + emit[tag]) : 0.f;
          vm = fmaxf(vm, u[rt][r]);
        }
      vm = fmaxf(vm, __shfl_xor(vm, 16, 64));
      vm = fmaxf(vm, __shfl_xor(vm, 32, 64));
      m0 = vm;
#pragma unroll
      for (int rt = 0; rt < 8; ++rt)
#pragma unroll
        for (int r = 0; r < 4; ++r)
          u[rt][r] = (col == 0) ? __expf(u[rt][r] - vm) : 1.0f;
    } else {
#pragma unroll
      for (int rt = 0; rt < 8; ++rt)
#pragma unroll
        for (int r = 0; r < 4; ++r) u[rt][r] = 1.0f;
    }
#pragma unroll
    for (int kt = 0; kt < 4; ++kt) {
      unsigned lo = (unsigned)__builtin_amdgcn_cvt_pk_fp8_f32(u[2*kt][0], u[2*kt][1], 0, false);
      lo = (unsigned)__builtin_amdgcn_cvt_pk_fp8_f32(u[2*kt][2], u[2*kt][3], (int)lo, true);
      unsigned hi = (unsigned)__builtin_amdgcn_cvt_pk_fp8_f32(u[2*kt+1][0], u[2*kt+1][1], 0, false);
      hi = (unsigned)__builtin_amdgcn_cvt_pk_fp8_f32(u[2*kt+1][2], u[2*kt+1][3], (int)hi, true);
      b[kt] = (long)(((unsigned long long)hi << 32) | lo);
    }
  }

  // depth-4 prefetch of E rows (2 x uint4 per row per lane)
  const int t0 = (gc == 0) ? 1 : (gc * LCH - BURN);
  uint4 pf[4][2];
#pragma unroll
  for (int d = 0; d < 4; ++d) {
    const unsigned char* p = Eb + ((size_t)(t0 + d) << 7) + g * 16;
    pf[d][0] = *(const uint4*)p;
    pf[d][1] = *(const uint4*)(p + 64);
  }

  float acc = 0.f;

#pragma unroll
  for (int s = 0; s < NSTEP; ++s) {
    // unpack E (replaces 32 expf of earlier rounds)
    float e[8][4];
#pragma unroll
    for (int h = 0; h < 2; ++h) {
      const uint4 P = pf[s & 3][h];
      const unsigned dws[4] = {P.x, P.y, P.z, P.w};
#pragma unroll
      for (int j = 0; j < 4; ++j) {
        const f32x2 lo = __builtin_amdgcn_cvt_pk_f32_fp8((int)dws[j], false);
        const f32x2 hi = __builtin_amdgcn_cvt_pk_f32_fp8((int)dws[j], true);
        e[4 * h + j][0] = lo[0];
        e[4 * h + j][1] = lo[1];
        e[4 * h + j][2] = hi[0];
        e[4 * h + j][3] = hi[1];
      }
    }
    // prefetch row s+4
    if (s < NSTEP - 4) {
      const unsigned char* p = Eb + ((size_t)(t0 + s + 4) << 7) + g * 16;
      pf[s & 3][0] = *(const uint4*)p;
      pf[s & 3][1] = *(const uint4*)(p + 64);
    }

    // c = A x b
    f32x4 c[8];
#pragma unroll
    for (int rt = 0; rt < 8; ++rt) c[rt] = (f32x4){0.f, 0.f, 0.f, 0.f};
#pragma unroll
    for (int kt = 0; kt < 4; ++kt)
#pragma unroll
      for (int rt = 0; rt < 8; ++rt)
        c[rt] = __builtin_amdgcn_mfma_f32_16x16x32_fp8_fp8(a[rt][kt], b[kt], c[rt], 0, 0, 0);

    // w = c * E; per-step rescale; dc = log(vm) + 1 (constant folded at end)
    float wv[8][4];
    float vm = -1e30f;
#pragma unroll
    for (int rt = 0; rt < 8; ++rt)
#pragma unroll
      for (int r = 0; r < 4; ++r) {
        wv[rt][r] = c[rt][r] * e[rt][r];
        vm = fmaxf(vm, wv[rt][r]);
      }
    vm = fmaxf(vm, __shfl_xor(vm, 16, 64));
    vm = fmaxf(vm, __shfl_xor(vm, 32, 64));
    const bool on = (gc == 0) ? (s <= LCH - 2) : (s >= BURN);
    if (on) acc += __logf(vm);
    const float rinv = __frcp_rn(vm);
#pragma unroll
    for (int kt = 0; kt < 4; ++kt) {
      const float s0 = wv[2*kt][0] * rinv,   s1 = wv[2*kt][1] * rinv;
      const float s2 = wv[2*kt][2] * rinv,   s3 = wv[2*kt][3] * rinv;
      const float s4 = wv[2*kt+1][0] * rinv, s5 = wv[2*kt+1][1] * rinv;
      const float s6 = wv[2*kt+1][2] * rinv, s7 = wv[2*kt+1][3] * rinv;
      unsigned lo = (unsigned)__builtin_amdgcn_cvt_pk_fp8_f32(s0, s1, 0, false);
      lo = (unsigned)__builtin_amdgcn_cvt_pk_fp8_f32(s2, s3, (int)lo, true);
      unsigned hi = (unsigned)__builtin_amdgcn_cvt_pk_fp8_f32(s4, s5, 0, false);
      hi = (unsigned)__builtin_amdgcn_cvt_pk_fp8_f32(s6, s7, (int)hi, true);
      b[kt] = (long)(((unsigned long long)hi << 32) | lo);
    }

    if (s == NSTEP - 1 && gw == NWAVE - 1) {
      float lse = 0.f;
#pragma unroll
      for (int rt = 0; rt < 8; ++rt)
#pragma unroll
        for (int r = 0; r < 4; ++r)
          lse += (wv[rt][r] * rinv) * __expf(etrans[16 * rt + 4 * g + r]);
      lse += __shfl_xor(lse, 16, 64);
      lse += __shfl_xor(lse, 32, 64);
      if (l == 15) atomicAdd(&ws[2], (double)lse);
    }
  }

  // per-chunk compensation: E carries e^-1 per step on counted steps.
  // chunk 0: dc_0=m0 + 7 counted steps; others: 8 counted steps.
  const float accf = acc + ((gc == 0) ? (m0 + 7.0f) : 8.0f);
  float av = (g == 0) ? accf : 0.f;
#pragma unroll
  for (int off = 1; off < 64; off <<= 1) av += __shfl_xor(av, off, 64);
  if (l == 0) atomicAdd(&ws[0], (double)av);

  // completion ticket: last block writes the output
  __syncthreads();
  if (threadIdx.x == 0) {
    __threadfence();
    const unsigned t = atomicAdd((unsigned*)&ws[3], 1u);
    if (t == NFWDB - 1) {
      const double d0 = atomicAdd(&ws[0], 0.0);
      const double d1 = atomicAdd(&ws[1], 0.0);
      const double d2 = atomicAdd(&ws[2], 0.0);
      out[0] = (float)(d0 + log(d2) - d1);
    }
  }
}

// ===========================================================================
// FALLBACK PATH (R10, proven) — used only if ws_size < 34 MB
// ===========================================================================
__global__ void crf_setup(const float* __restrict__ trans, uint4* __restrict__ q4)
{
  const int l = threadIdx.x, col = l & 15, grp = l >> 4;
  for (int rt = 0; rt < 8; ++rt) {
    const int outtag = 16 * rt + col;
    for (int kp = 0; kp < 2; ++kp) {
      unsigned r[4];
      for (int h = 0; h < 2; ++h) {
        const int kt = kp * 2 + h;
        float q[8];
        for (int j = 0; j < 8; ++j) {
          const int k = 32 * kt + 4 * grp + (j & 3) + 16 * (j >> 2);
          q[j] = __expf(trans[k * NTAG + outtag]);
        }
        unsigned lo = (unsigned)__builtin_amdgcn_cvt_pk_fp8_f32(q[0], q[1], 0, false);
        lo = (unsigned)__builtin_amdgcn_cvt_pk_fp8_f32(q[2], q[3], (int)lo, true);
        unsigned hi = (unsigned)__builtin_amdgcn_cvt_pk_fp8_f32(q[4], q[5], 0, false);
        hi = (unsigned)__builtin_amdgcn_cvt_pk_fp8_f32(q[6], q[7], (int)hi, true);
        r[h * 2] = lo; r[h * 2 + 1] = hi;
      }
      q4[(rt * 2 + kp) * 64 + l] = make_uint4(r[0], r[1], r[2], r[3]);
    }
  }
}

__global__ __launch_bounds__(256, 2) void crf_fwd(
    const float* __restrict__ emit, const float* __restrict__ strans,
    const float* __restrict__ etrans, const uint4* __restrict__ q4,
    double* __restrict__ ws)
{
  const int w_id = threadIdx.x >> 6, l = threadIdx.x & 63;
  const int col = l & 15, grp = l >> 4;
  const int gw = blockIdx.x * 4 + w_id, gc = gw * 16 + col;
  long a[8][4];
#pragma unroll
  for (int rt = 0; rt < 8; ++rt)
#pragma unroll
    for (int kp = 0; kp < 2; ++kp) {
      uint4 v = q4[(rt * 2 + kp) * 64 + l];
      a[rt][2 * kp]     = (long)(((unsigned long long)v.y << 32) | v.x);
      a[rt][2 * kp + 1] = (long)(((unsigned long long)v.w << 32) | v.z);
    }
  float m0 = 0.f;
  long b[4];
  {
    float u[8][4];
    if (gw == 0) {
      float vm = -1e30f;
#pragma unroll
      for (int rt = 0; rt < 8; ++rt)
#pragma unroll
        for (int r = 0; r < 4; ++r) {
          const int tag = 16 * rt + 4 * grp + r;
          u[rt][r] = (col == 0) ? (strans[tag] + emit[tag]) : 0.f;
          vm = fmaxf(vm, u[rt][r]);
        }
      vm = fmaxf(vm, __shfl_xor(vm, 16, 64));
      vm = fmaxf(vm, __shfl_xor(vm, 32, 64));
      m0 = vm;
#pragma unroll
      for (int rt = 0; rt < 8; ++rt)
#pragma unroll
        for (int r = 0; r < 4; ++r)
          u[rt][r] = (col == 0) ? __expf(u[rt][r] - vm) : 1.0f;
    } else {
#pragma unroll
      for (int rt = 0; rt < 8; ++rt)
#pragma unroll
        for (int r = 0; r < 4; ++r) u[rt][r] = 1.0f;
    }
#pragma unroll
    for (int kt = 0; kt < 4; ++kt) {
      unsigned lo = (unsigned)__builtin_amdgcn_cvt_pk_fp8_f32(u[2*kt][0], u[2*kt][1], 0, false);
      lo = (unsigned)__builtin_amdgcn_cvt_pk_fp8_f32(u[2*kt][2], u[2*kt][3], (int)lo, true);
      unsigned hi = (unsigned)__builtin_amdgcn_cvt_pk_fp8_f32(u[2*kt+1][0], u[2*kt+1][1], 0, false);
      hi = (unsigned)__builtin_amdgcn_cvt_pk_fp8_f32(u[2*kt+1][2], u[2*kt+1][3], (int)hi, true);
      b[kt] = (long)(((unsigned long long)hi << 32) | lo);
    }
  }
  const int t0 = (gc == 0) ? 1 : (gc * LCH - BURN);
  float4 pf[2][8];
  {
    const float* e0 = emit + ((size_t)t0 << 7) + 4 * grp;
    const float* e1 = emit + ((size_t)(t0 + 1) << 7) + 4 * grp;
#pragma unroll
    for (int rt = 0; rt < 8; ++rt) {
      pf[0][rt] = *(const float4*)(e0 + 16 * rt);
      pf[1][rt] = *(const float4*)(e1 + 16 * rt);
    }
  }
  float acc = 0.f;
#pragma unroll
  for (int s = 0; s < NSTEP; ++s) {
    float e[8][4];
#pragma unroll
    for (int rt = 0; rt < 8; ++rt) {
      e[rt][0] = __expf(pf[s & 1][rt].x - C9);
      e[rt][1] = __expf(pf[s & 1][rt].y - C9);
      e[rt][2] = __expf(pf[s & 1][rt].z - C9);
      e[rt][3] = __expf(pf[s & 1][rt].w - C9);
    }
    if (s < NSTEP - 2) {
      const float* ep = emit + ((size_t)(t0 + s + 2) << 7) + 4 * grp;
#pragma unroll
      for (int rt = 0; rt < 8; ++rt) pf[s & 1][rt] = *(const float4*)(ep + 16 * rt);
    }
    f32x4 c[8];
#pragma unroll
    for (int rt = 0; rt < 8; ++rt) c[rt] = (f32x4){0.f, 0.f, 0.f, 0.f};
#pragma unroll
    for (int kt = 0; kt < 4; ++kt)
#pragma unroll
      for (int rt = 0; rt < 8; ++rt)
        c[rt] = __builtin_amdgcn_mfma_f32_16x16x32_fp8_fp8(a[rt][kt], b[kt], c[rt], 0, 0, 0);
    float wv[8][4];
    float vm = -1e30f;
#pragma unroll
    for (int rt = 0; rt < 8; ++rt)
#pragma unroll
      for (int r = 0; r < 4; ++r) {
        wv[rt][r] = c[rt][r] * e[rt][r];
        vm = fmaxf(vm, wv[rt][r]);
      }
    vm = fmaxf(vm, __shfl_xor(vm, 16, 64));
    vm = fmaxf(vm, __shfl_xor(vm, 32, 64));
    const bool on = (gc == 0) ? (s <= LCH - 2) : (s >= BURN);
    if (on) acc += __logf(vm);
    const float rinv = __frcp_rn(vm);
#pragma unroll
    for (int kt = 0; kt < 4; ++kt) {
      const float s0 = wv[2*kt][0] * rinv,   s1 = wv[2*kt][1] * rinv;
      const float s2 = wv[2*kt][2] * rinv,   s3 = wv[2*kt][3] * rinv;
      const float s4 = wv[2*kt+1][0] * rinv, s5 = wv[2*kt+1][1] * rinv;
      const float s6 = wv[2*kt+1][2] * rinv, s7 = wv[2*kt+1][3] * rinv;
      unsigned lo = (unsigned)__builtin_amdgcn_cvt_pk_fp8_f32(s0, s1, 0, false);
      lo = (unsigned)__builtin_amdgcn_cvt_pk_fp8_f32(s2, s3, (int)lo, true);
      unsigned hi = (unsigned)__builtin_amdgcn_cvt_pk_fp8_f32(s4, s5, 0, false);
      hi = (unsigned)__builtin_amdgcn_cvt_pk_fp8_f32(s6, s7, (int)hi, true);
      b[kt] = (long)(((unsigned long long)hi << 32) | lo);
    }
    if (s == NSTEP - 1 && gw == NWAVE - 1) {
      float lse = 0.f;
#pragma unroll
      for (int rt = 0; rt < 8; ++rt)
#pragma unroll
        for (int r = 0; r < 4; ++r)
          lse += (wv[rt][r] * rinv) * __expf(etrans[16 * rt + 4 * grp + r]);
      lse += __shfl_xor(lse, 16, 64);
      lse += __shfl_xor(lse, 32, 64);
      if (l == 15) atomicAdd(&ws[2], (double)lse);
    }
  }
  const float accf = acc + ((gc == 0) ? (m0 + K63LN2) : K72LN2);
  float av = (grp == 0) ? accf : 0.f;
#pragma unroll
  for (int off = 1; off < 64; off <<= 1) av += __shfl_xor(av, off, 64);
  if (l == 0) atomicAdd(&ws[0], (double)av);
}

__global__ void crf_score(const float* __restrict__ emit, const int* __restrict__ y,
                          const float* __restrict__ trans, const float* __restrict__ strans,
                          const float* __restrict__ etrans, double* __restrict__ ws)
{
  __shared__ float sred[4];
  int idx0 = blockIdx.x * 256 + threadIdx.x;
  float v = 0.f;
  for (int t = idx0; t < T_LEN - 1; t += NSCOREB * 256) {
    int yt = y[t], yn = y[t + 1];
    v += trans[yt * NTAG + yn] + emit[(size_t)t * NTAG + yt];
  }
  if (idx0 == 0) {
    int yl = y[T_LEN - 1];
    v += strans[y[0]] + etrans[yl] + emit[(size_t)(T_LEN - 1) * NTAG + yl];
  }
#pragma unroll
  for (int off = 1; off < 64; off <<= 1) v += __shfl_xor(v, off, 64);
  if ((threadIdx.x & 63) == 0) sred[threadIdx.x >> 6] = v;
  __syncthreads();
  if (threadIdx.x == 0)
    atomicAdd(&ws[1], (double)(sred[0] + sred[1] + sred[2] + sred[3]));
}

__global__ void crf_final(const double* __restrict__ ws, float* __restrict__ out)
{
  out[0] = (float)(ws[0] + log(ws[2]) - ws[1]);
}

// ---------------------------------------------------------------------------
extern "C" void kernel_launch(void* const* d_in, const int* in_sizes, int n_in,
                              void* d_out, int out_size, void* d_ws, size_t ws_size,
                              hipStream_t stream)
{
  const float* emit   = (const float*)d_in[0];
  const int*   y      = (const int*)d_in[1];
  const float* trans  = (const float*)d_in[2];
  const float* strans = (const float*)d_in[3];
  const float* etrans = (const float*)d_in[4];
  float*  out = (float*)d_out;
  double* ws  = (double*)d_ws;
  uint4*  q4  = (uint4*)((char*)d_ws + 128);            // 16 KB A-fragments
  unsigned* Ed = (unsigned*)((char*)d_ws + 128 + 16384); // 33.55 MB fp8 E

  const size_t need = 128 + 16384 + (size_t)T_LEN * NTAG;  // ~33.57 MB

  hipMemsetAsync(ws, 0, 8 * sizeof(double), stream);

  if (ws_size >= need) {
    crf_prep<<<dim3(NPREPB), dim3(256), 0, stream>>>(
        emit, y, trans, strans, etrans, Ed, q4, ws);
    crf_main<<<dim3(NFWDB), dim3(256), 0, stream>>>(
        emit, strans, etrans, (const unsigned char*)Ed, q4, ws, out);
  } else {
    crf_setup<<<dim3(1), dim3(64), 0, stream>>>(trans, q4);
    crf_score<<<dim3(NSCOREB), dim3(256), 0, stream>>>(emit, y, trans, strans, etrans, ws);
    crf_fwd  <<<dim3(NFWDB), dim3(256), 0, stream>>>(emit, strans, etrans, q4, ws);
    crf_final<<<dim3(1), dim3(1), 0, stream>>>(ws, out);
  }
}